// Round 2
// baseline (526.848 us; speedup 1.0000x reference)
//
#include <hip/hip_runtime.h>
#include <stdint.h>

// MSAColumnGlobalAttention: B=1, S=2048, R=384, D=64, H=8, C=8, HC=64
// Buffers are FLOAT32 (per reference dtypes); comparison is bf16-tolerance,
// so internal compute may use bf16 (kv scratch, MFMA fragments).
//
// K1: per (s-chunk, r): LN stats + k/v (bf16 scratch) + masked q partial sums
// K2: per r: q_avg -> q, logits (registers), softmax, o[h][c]
// K3: per (s-chunk, r): LN rows -> MFMA (mln@Wg) -> sigmoid*o -> MFMA (@Wo) -> +bo + residual

#define DEV __device__ __forceinline__

typedef __attribute__((ext_vector_type(8))) short short8;   // 8 bf16 (4 VGPRs) MFMA A/B frag
typedef __attribute__((ext_vector_type(4))) float floatx4;  // MFMA C/D frag

static constexpr int S_DIM = 2048;
static constexpr int R_DIM = 384;

// ws layout (bytes)
static constexpr size_t KV_OFF    = 0;                       // bf16 [384][2048][16] (k0..7, v0..7) = 25165824
static constexpr size_t STATS_OFF = 25165824;                // f32  [384][2048][2]  (mu, rstd)     = 6291456
static constexpr size_t QPART_OFF = 31457280;                // f32  [384][8][72]    (64 q sums + cnt)
static constexpr size_t O_OFF     = 32342016;                // f32  [384][64]

DEV float bf2f(uint32_t u) { union { uint32_t i; float f; } c; c.i = u << 16; return c.f; }
DEV uint16_t f2bf(float f) {
  union { float f; uint32_t i; } c; c.f = f;
  return (uint16_t)((c.i + 0x7FFFu + ((c.i >> 16) & 1u)) >> 16); // RNE
}
DEV void unpack8(uint4 w, float* x) {
  x[0] = bf2f(w.x & 0xffff); x[1] = bf2f(w.x >> 16);
  x[2] = bf2f(w.y & 0xffff); x[3] = bf2f(w.y >> 16);
  x[4] = bf2f(w.z & 0xffff); x[5] = bf2f(w.z >> 16);
  x[6] = bf2f(w.w & 0xffff); x[7] = bf2f(w.w >> 16);
}
DEV uint4 pack8(const float* x) {
  uint4 w;
  w.x = (uint32_t)f2bf(x[0]) | ((uint32_t)f2bf(x[1]) << 16);
  w.y = (uint32_t)f2bf(x[2]) | ((uint32_t)f2bf(x[3]) << 16);
  w.z = (uint32_t)f2bf(x[4]) | ((uint32_t)f2bf(x[5]) << 16);
  w.w = (uint32_t)f2bf(x[6]) | ((uint32_t)f2bf(x[7]) << 16);
  return w;
}

// ---------------- K1 ----------------
__global__ __launch_bounds__(256) void k1_ln_kv(
    const float* __restrict__ M, const float* __restrict__ mask,
    const float* __restrict__ lng, const float* __restrict__ lnb,
    const float* __restrict__ Wk, const float* __restrict__ Wv,
    uint16_t* __restrict__ kv, float* __restrict__ stats, float* __restrict__ qpart)
{
  __shared__ float WkvL[64 * 16];  // [d][c]: k 0..7, v 8..15
  __shared__ float lngL[64], lnbL[64];
  __shared__ float redq[4][64];
  __shared__ float redc[4];
  const int tid = threadIdx.x;
  const int r = blockIdx.y;
  const int s = blockIdx.x * 256 + tid;

  if (tid < 64) {
    lngL[tid] = lng[tid];
    lnbL[tid] = lnb[tid];
#pragma unroll
    for (int c = 0; c < 8; ++c) {
      WkvL[tid * 16 + c]     = Wk[tid * 8 + c];
      WkvL[tid * 16 + 8 + c] = Wv[tid * 8 + c];
    }
  }
  __syncthreads();

  const size_t row = (size_t)s * R_DIM + r;
  const float4* mp = (const float4*)(M + row * 64);
  float x[64];
#pragma unroll
  for (int i = 0; i < 16; ++i) {
    float4 w = mp[i];
    x[i * 4] = w.x; x[i * 4 + 1] = w.y; x[i * 4 + 2] = w.z; x[i * 4 + 3] = w.w;
  }

  float sum = 0.f, ss = 0.f;
#pragma unroll
  for (int d = 0; d < 64; ++d) { sum += x[d]; ss += x[d] * x[d]; }
  const float mu = sum * (1.f / 64.f);
  const float var = ss * (1.f / 64.f) - mu * mu;
  const float rstd = 1.f / sqrtf(var + 1e-5f);
  ((float2*)stats)[(size_t)r * S_DIM + s] = make_float2(mu, rstd);

  const float m = mask[row];
  float kp[8], vp[8];
#pragma unroll
  for (int c = 0; c < 8; ++c) { kp[c] = 0.f; vp[c] = 0.f; }
#pragma unroll
  for (int d = 0; d < 64; ++d) {
    const float xl = (x[d] - mu) * rstd * lngL[d] + lnbL[d];
    x[d] = xl * m;  // masked-q contribution
#pragma unroll
    for (int c = 0; c < 8; ++c) {
      kp[c] += xl * WkvL[d * 16 + c];
      vp[c] += xl * WkvL[d * 16 + 8 + c];
    }
  }
  uint4* kvp = (uint4*)kv;
  kvp[((size_t)r * S_DIM + s) * 2]     = pack8(kp);
  kvp[((size_t)r * S_DIM + s) * 2 + 1] = pack8(vp);

  // fold-exchange: sum x[0..63] across the wave's 64 lanes; lane L ends with
  // the column-sum for d=L in x[0]. Static indexing only (no scratch spill).
  const int lane = tid & 63, wv = tid >> 6;
#pragma unroll
  for (int st = 5; st >= 0; --st) {
    const int dist = 1 << st;
    const bool hi = (lane & dist) != 0;
#pragma unroll
    for (int j = 0; j < (1 << st); ++j) {
      const float send = hi ? x[j] : x[j + dist];
      const float recv = __shfl_xor(send, dist, 64);
      x[j] = (hi ? x[j + dist] : x[j]) + recv;
    }
  }
  float cnt = m;
#pragma unroll
  for (int off = 1; off < 64; off <<= 1) cnt += __shfl_xor(cnt, off, 64);

  redq[wv][lane] = x[0];
  if (lane == 0) redc[wv] = cnt;
  __syncthreads();
  if (tid < 64)
    qpart[((size_t)r * 8 + blockIdx.x) * 72 + tid] =
        redq[0][tid] + redq[1][tid] + redq[2][tid] + redq[3][tid];
  if (tid == 64)
    qpart[((size_t)r * 8 + blockIdx.x) * 72 + 64] = redc[0] + redc[1] + redc[2] + redc[3];
}

// ---------------- K2 ----------------
__global__ __launch_bounds__(256) void k2_attn(
    const float* __restrict__ Wq, const float* __restrict__ mask,
    const uint16_t* __restrict__ kv, const float* __restrict__ qpart,
    float* __restrict__ oG)
{
  __shared__ float qavgL[64], qLs[64];
  __shared__ float redmax[4][8], redden[4][8], redo[4][64];
  __shared__ float cntL;
  const int tid = threadIdx.x;
  const int r = blockIdx.x;
  const int lane = tid & 63, wv = tid >> 6;

  float qs = 0.f;
  if (tid < 65) {
#pragma unroll
    for (int c = 0; c < 8; ++c) qs += qpart[((size_t)r * 8 + c) * 72 + tid];
    if (tid == 64) cntL = qs;
  }
  __syncthreads();
  if (tid < 64) qavgL[tid] = qs / (cntL + 1e-10f);
  __syncthreads();
  if (tid < 64) {
    float a = 0.f;
    for (int d = 0; d < 64; ++d) a += qavgL[d] * Wq[d * 64 + tid];
    qLs[tid] = a * 0.35355339059327373f;  // C^-0.5
  }
  __syncthreads();

  // logits in registers: l[it*8+h], statically indexed via full unroll
  float l[64];
  float lm[8];
#pragma unroll
  for (int h = 0; h < 8; ++h) lm[h] = -3.0e38f;
  const uint4* kvp = (const uint4*)kv;
#pragma unroll
  for (int it = 0; it < 8; ++it) {
    const int s = it * 256 + tid;
    uint4 kw = kvp[((size_t)r * S_DIM + s) * 2];
    float k[8]; unpack8(kw, k);
    const float bias = (mask[(size_t)s * R_DIM + r] - 1.f) * 1e9f;
#pragma unroll
    for (int h = 0; h < 8; ++h) {
      float t = bias;
#pragma unroll
      for (int c = 0; c < 8; ++c) t += qLs[h * 8 + c] * k[c];
      l[it * 8 + h] = t;
      lm[h] = fmaxf(lm[h], t);
    }
  }
#pragma unroll
  for (int h = 0; h < 8; ++h)
#pragma unroll
    for (int off = 1; off < 64; off <<= 1) lm[h] = fmaxf(lm[h], __shfl_xor(lm[h], off, 64));
  if (lane == 0) {
#pragma unroll
    for (int h = 0; h < 8; ++h) redmax[wv][h] = lm[h];
  }
  __syncthreads();
  float gm[8];
#pragma unroll
  for (int h = 0; h < 8; ++h)
    gm[h] = fmaxf(fmaxf(redmax[0][h], redmax[1][h]), fmaxf(redmax[2][h], redmax[3][h]));

  float den[8], ao[64];
#pragma unroll
  for (int h = 0; h < 8; ++h) den[h] = 0.f;
#pragma unroll
  for (int i = 0; i < 64; ++i) ao[i] = 0.f;
#pragma unroll
  for (int it = 0; it < 8; ++it) {
    const int s = it * 256 + tid;
    uint4 vw = kvp[((size_t)r * S_DIM + s) * 2 + 1];
    float v[8]; unpack8(vw, v);
#pragma unroll
    for (int h = 0; h < 8; ++h) {
      const float w = __expf(l[it * 8 + h] - gm[h]);
      den[h] += w;
#pragma unroll
      for (int c = 0; c < 8; ++c) ao[h * 8 + c] += w * v[c];
    }
  }
  // fold-exchange ao: lane L ends with the wave sum for hc=L in ao[0]
#pragma unroll
  for (int st = 5; st >= 0; --st) {
    const int dist = 1 << st;
    const bool hi = (lane & dist) != 0;
#pragma unroll
    for (int j = 0; j < (1 << st); ++j) {
      const float send = hi ? ao[j] : ao[j + dist];
      const float recv = __shfl_xor(send, dist, 64);
      ao[j] = (hi ? ao[j + dist] : ao[j]) + recv;
    }
  }
#pragma unroll
  for (int h = 0; h < 8; ++h)
#pragma unroll
    for (int off = 1; off < 64; off <<= 1) den[h] += __shfl_xor(den[h], off, 64);

  redo[wv][lane] = ao[0];
  if (lane == 0) {
#pragma unroll
    for (int h = 0; h < 8; ++h) redden[wv][h] = den[h];
  }
  __syncthreads();
  if (tid < 64) {
    const float o = redo[0][tid] + redo[1][tid] + redo[2][tid] + redo[3][tid];
    const int h = tid >> 3;
    const float dd = redden[0][h] + redden[1][h] + redden[2][h] + redden[3][h];
    oG[(size_t)r * 64 + tid] = o / dd;
  }
}

// ---------------- K3 (MFMA) ----------------
__global__ __launch_bounds__(256, 2) void k3_out(
    const float* __restrict__ M, const float* __restrict__ stats,
    const float* __restrict__ oG,
    const float* __restrict__ Wg, const float* __restrict__ bg,
    const float* __restrict__ Wo, const float* __restrict__ bo,
    const float* __restrict__ lng, const float* __restrict__ lnb,
    float* __restrict__ out)
{
  constexpr int MSTR = 72;               // bf16 row stride; 144 B = 9*16 keeps 16B align, breaks pow2 banks
  __shared__ uint16_t mlnL[256 * MSTR];  // mln -> T -> OUT (each wave touches only its own 64 rows)
  __shared__ uint16_t WgT[64 * MSTR];    // WgT[hc][d] = Wg[d][hc] (B operand [n][k])
  __shared__ uint16_t WoT[64 * MSTR];    // WoT[d][hc] = Wo[hc][d] (B operand [n][k])
  __shared__ float oLs[64], lngL[64], lnbL[64];
  const int tid = threadIdx.x;
  const int r = blockIdx.y;
  const int s = blockIdx.x * 256 + tid;

#pragma unroll
  for (int i = 0; i < 16; ++i) {
    const int idx = i * 256 + tid;           // 4096 weight elems
    const int a = idx >> 6, b = idx & 63;
    WgT[b * MSTR + a] = f2bf(Wg[idx]);       // a=d, b=hc
    WoT[b * MSTR + a] = f2bf(Wo[idx]);       // a=hc, b=d
  }
  if (tid < 64) {
    oLs[tid] = oG[(size_t)r * 64 + tid];
    lngL[tid] = lng[tid];
    lnbL[tid] = lnb[tid];
  }
  __syncthreads();

  // phase 1: LN -> mlnL (bf16), one row per thread
  const size_t row = (size_t)s * R_DIM + r;
  const float4* mp = (const float4*)(M + row * 64);
  const float2 st = ((const float2*)stats)[(size_t)r * S_DIM + s];
  const float mu = st.x, rstd = st.y;
#pragma unroll
  for (int i = 0; i < 8; ++i) {
    float4 w0 = mp[i * 2], w1 = mp[i * 2 + 1];
    float yy[8] = {w0.x, w0.y, w0.z, w0.w, w1.x, w1.y, w1.z, w1.w};
#pragma unroll
    for (int u = 0; u < 8; ++u) yy[u] = (yy[u] - mu) * rstd * lngL[i * 8 + u] + lnbL[i * 8 + u];
    *(uint4*)(&mlnL[tid * MSTR + i * 8]) = pack8(yy);
  }
  __syncthreads();

  const int lane = tid & 63;
  const int wrow0 = tid & 192;        // wave's base row in tile
  const int mrow = lane & 15;         // n / col index
  const int quad = lane >> 4;

  // B fragments in registers: B[k = quad*8+j][n = lane&15]
  short8 wgB[4][2], woB[4][2];
#pragma unroll
  for (int nt = 0; nt < 4; ++nt)
#pragma unroll
    for (int kk = 0; kk < 2; ++kk) {
      wgB[nt][kk] = *(const short8*)(&WgT[(nt * 16 + mrow) * MSTR + kk * 32 + quad * 8]);
      woB[nt][kk] = *(const short8*)(&WoT[(nt * 16 + mrow) * MSTR + kk * 32 + quad * 8]);
    }
  float og[4], bgr[4], bor[4];
#pragma unroll
  for (int nt = 0; nt < 4; ++nt) {
    og[nt] = oLs[nt * 16 + mrow];
    bgr[nt] = bg[nt * 16 + mrow];
    bor[nt] = bo[nt * 16 + mrow];
  }

  // GEMM1: G = mln @ Wg ; T = sigmoid(G+bg)*o ; T -> LDS (A layout via C/D scatter)
#pragma unroll
  for (int mt = 0; mt < 4; ++mt) {
    const int arow = (wrow0 + mt * 16 + mrow) * MSTR + quad * 8;  // A[m=lane&15][k=quad*8+j]
    short8 a0 = *(const short8*)(&mlnL[arow]);
    short8 a1 = *(const short8*)(&mlnL[arow + 32]);
#pragma unroll
    for (int nt = 0; nt < 4; ++nt) {
      floatx4 c = {0.f, 0.f, 0.f, 0.f};
      c = __builtin_amdgcn_mfma_f32_16x16x32_bf16(a0, wgB[nt][0], c, 0, 0, 0);
      c = __builtin_amdgcn_mfma_f32_16x16x32_bf16(a1, wgB[nt][1], c, 0, 0, 0);
#pragma unroll
      for (int i = 0; i < 4; ++i) {  // C/D: row = quad*4+i, col = lane&15
        const float z = c[i] + bgr[nt];
        const float g = 1.0f / (1.0f + __expf(-z));
        mlnL[(wrow0 + mt * 16 + quad * 4 + i) * MSTR + nt * 16 + mrow] = f2bf(g * og[nt]);
      }
    }
  }
  __syncthreads();

  // GEMM2: OUT = T @ Wo + bo -> LDS
#pragma unroll
  for (int mt = 0; mt < 4; ++mt) {
    const int arow = (wrow0 + mt * 16 + mrow) * MSTR + quad * 8;
    short8 a0 = *(const short8*)(&mlnL[arow]);
    short8 a1 = *(const short8*)(&mlnL[arow + 32]);
#pragma unroll
    for (int nt = 0; nt < 4; ++nt) {
      floatx4 c = {0.f, 0.f, 0.f, 0.f};
      c = __builtin_amdgcn_mfma_f32_16x16x32_bf16(a0, woB[nt][0], c, 0, 0, 0);
      c = __builtin_amdgcn_mfma_f32_16x16x32_bf16(a1, woB[nt][1], c, 0, 0, 0);
#pragma unroll
      for (int i = 0; i < 4; ++i)
        mlnL[(wrow0 + mt * 16 + quad * 4 + i) * MSTR + nt * 16 + mrow] = f2bf(c[i] + bor[nt]);
    }
  }
  __syncthreads();

  // epilogue: residual + coalesced f32 store (per-thread row)
  float4* op = (float4*)(out + row * 64);
#pragma unroll
  for (int i = 0; i < 8; ++i) {
    float4 w0 = mp[i * 2], w1 = mp[i * 2 + 1];
    uint4 tv = *(const uint4*)(&mlnL[tid * MSTR + i * 8]);
    float yy[8]; unpack8(tv, yy);
    float4 o0 = make_float4(w0.x + yy[0], w0.y + yy[1], w0.z + yy[2], w0.w + yy[3]);
    float4 o1 = make_float4(w1.x + yy[4], w1.y + yy[5], w1.z + yy[6], w1.w + yy[7]);
    op[i * 2] = o0;
    op[i * 2 + 1] = o1;
  }
}

extern "C" void kernel_launch(void* const* d_in, const int* in_sizes, int n_in,
                              void* d_out, int out_size, void* d_ws, size_t ws_size,
                              hipStream_t stream)
{
  const float* M    = (const float*)d_in[0];
  const float* mask = (const float*)d_in[1];
  const float* lng  = (const float*)d_in[2];
  const float* lnb  = (const float*)d_in[3];
  const float* Wq   = (const float*)d_in[4];
  const float* Wk   = (const float*)d_in[5];
  const float* Wv   = (const float*)d_in[6];
  const float* Wg   = (const float*)d_in[7];
  const float* bg   = (const float*)d_in[8];
  const float* Wo   = (const float*)d_in[9];
  const float* bo   = (const float*)d_in[10];
  float* out = (float*)d_out;

  char* ws = (char*)d_ws;
  uint16_t* kvB  = (uint16_t*)(ws + KV_OFF);
  float* statsB  = (float*)(ws + STATS_OFF);
  float* qpartB  = (float*)(ws + QPART_OFF);
  float* oB      = (float*)(ws + O_OFF);

  k1_ln_kv<<<dim3(8, 384), 256, 0, stream>>>(M, mask, lng, lnb, Wk, Wv, kvB, statsB, qpartB);
  k2_attn<<<dim3(384), 256, 0, stream>>>(Wq, mask, kvB, qpartB, oB);
  k3_out<<<dim3(8, 384), 256, 0, stream>>>(M, statsB, oB, Wg, bg, Wo, bo, lng, lnb, out);
}

// Round 3
// 469.406 us; speedup vs baseline: 1.1224x; 1.1224x over previous
//
#include <hip/hip_runtime.h>
#include <stdint.h>

// MSAColumnGlobalAttention: B=1, S=2048, R=384, D=64, H=8, C=8, HC=64
// Buffers f32; bf16 internally (kv scratch, MFMA frags) within bf16 tolerance.
//
// Coalescing scheme (all big streams): a wave covers 64 consecutive s-rows of a
// fixed r; instruction j accesses rows {j*4 + lane>>4} with 16 lanes dense per
// row (col = (lane&15)*4 floats) -> 4x256B dense chunks = 8 lines/instr,
// instead of 64 scattered lines/instr (round-2's 2.26 TB/s ceiling).

#define DEV __device__ __forceinline__

typedef __attribute__((ext_vector_type(8))) short short8;   // 8 bf16 (4 VGPRs) MFMA A/B frag
typedef __attribute__((ext_vector_type(4))) float floatx4;  // MFMA C/D frag

static constexpr int S_DIM = 2048;
static constexpr int R_DIM = 384;

// ws layout (bytes)
static constexpr size_t KV_OFF    = 0;                       // bf16 [384][2048][16] (k0..7, v0..7) = 25165824
static constexpr size_t STATS_OFF = 25165824;                // f32  [384][2048][2]  (mu, rstd)     = 6291456
static constexpr size_t QPART_OFF = 31457280;                // f32  [384][8][72]    (64 q sums + cnt)
static constexpr size_t O_OFF     = 32342016;                // f32  [384][64]

DEV float bf2f(uint32_t u) { union { uint32_t i; float f; } c; c.i = u << 16; return c.f; }
DEV uint16_t f2bf(float f) {
  union { float f; uint32_t i; } c; c.f = f;
  return (uint16_t)((c.i + 0x7FFFu + ((c.i >> 16) & 1u)) >> 16); // RNE
}
DEV void unpack8(uint4 w, float* x) {
  x[0] = bf2f(w.x & 0xffff); x[1] = bf2f(w.x >> 16);
  x[2] = bf2f(w.y & 0xffff); x[3] = bf2f(w.y >> 16);
  x[4] = bf2f(w.z & 0xffff); x[5] = bf2f(w.z >> 16);
  x[6] = bf2f(w.w & 0xffff); x[7] = bf2f(w.w >> 16);
}

// ---------------- K1: LN stats + kv (MFMA) + masked-q partials ----------------
__global__ __launch_bounds__(256) void k1_ln_kv(
    const float* __restrict__ M, const float* __restrict__ mask,
    const float* __restrict__ lng, const float* __restrict__ lnb,
    const float* __restrict__ Wk, const float* __restrict__ Wv,
    uint16_t* __restrict__ kv, float* __restrict__ stats, float* __restrict__ qpart)
{
  __shared__ uint16_t mlnL[256 * 72];   // 36864 B, LN'd rows (bf16)
  __shared__ uint16_t WkvT[16 * 72];    // B operand [n=c(0..7 k, 8..15 v)][k=d]
  __shared__ uint16_t kvL[256 * 16];    // MFMA C -> coalesced store staging
  __shared__ float redq[4][64];
  __shared__ float redc[4];

  const int tid = threadIdx.x;
  const int r = blockIdx.y;
  const int s_base = blockIdx.x * 256;
  const int w = tid >> 6, lane = tid & 63;
  const int g = lane >> 4, c4 = lane & 15;

  // stage WkvT[n][d]
#pragma unroll
  for (int i = 0; i < 4; ++i) {
    const int e = i * 256 + tid;        // 1024 elems
    const int n = e >> 6, d = e & 63;
    const float val = (n < 8) ? Wk[d * 8 + n] : Wv[d * 8 + (n - 8)];
    WkvT[n * 72 + d] = f2bf(val);
  }
  const float4 lngv = ((const float4*)lng)[c4];
  const float4 lnbv = ((const float4*)lnb)[c4];

  float qacc[4] = {0.f, 0.f, 0.f, 0.f};
  float cacc = 0.f;

#pragma unroll
  for (int j = 0; j < 16; ++j) {
    const int row_local = w * 64 + j * 4 + g;
    const int s = s_base + row_local;
    const size_t grow = (size_t)s * R_DIM + r;
    const float4 x = ((const float4*)(M + grow * 64))[c4];
    float sum = x.x + x.y + x.z + x.w;
    float ss = x.x * x.x + x.y * x.y + x.z * x.z + x.w * x.w;
#pragma unroll
    for (int off = 1; off < 16; off <<= 1) {
      sum += __shfl_xor(sum, off, 64);
      ss  += __shfl_xor(ss, off, 64);
    }
    const float mu = sum * (1.f / 64.f);
    const float var = ss * (1.f / 64.f) - mu * mu;
    const float rstd = 1.f / sqrtf(var + 1e-5f);
    if (c4 == 0) ((float2*)stats)[(size_t)r * S_DIM + s] = make_float2(mu, rstd);
    float y[4];
    y[0] = (x.x - mu) * rstd * lngv.x + lnbv.x;
    y[1] = (x.y - mu) * rstd * lngv.y + lnbv.y;
    y[2] = (x.z - mu) * rstd * lngv.z + lnbv.z;
    y[3] = (x.w - mu) * rstd * lngv.w + lnbv.w;
    uint2 p;
    p.x = (uint32_t)f2bf(y[0]) | ((uint32_t)f2bf(y[1]) << 16);
    p.y = (uint32_t)f2bf(y[2]) | ((uint32_t)f2bf(y[3]) << 16);
    *(uint2*)&mlnL[row_local * 72 + c4 * 4] = p;
    const float mval = mask[grow];
    qacc[0] += mval * y[0]; qacc[1] += mval * y[1];
    qacc[2] += mval * y[2]; qacc[3] += mval * y[3];
    cacc += mval;
  }

  // reduce qacc across the 4 row-groups (lanes sharing c4)
#pragma unroll
  for (int off = 16; off < 64; off <<= 1) {
#pragma unroll
    for (int i = 0; i < 4; ++i) qacc[i] += __shfl_xor(qacc[i], off, 64);
  }
#pragma unroll
  for (int off = 1; off < 64; off <<= 1) cacc += __shfl_xor(cacc, off, 64);
  if (lane < 16) {
    float4 qv = make_float4(qacc[0], qacc[1], qacc[2], qacc[3]);
    *(float4*)&redq[w][c4 * 4] = qv;
  }
  if (lane == 0) redc[w] = cacc * (1.f / 16.f);  // each row counted by 16 lanes
  __syncthreads();

  // MFMA: kv = mln @ Wkv  (B[n=lane&15][k=g*8+j (+32)])
  const short8 b0 = *(const short8*)&WkvT[c4 * 72 + g * 8];
  const short8 b1 = *(const short8*)&WkvT[c4 * 72 + 32 + g * 8];
#pragma unroll
  for (int mt = 0; mt < 4; ++mt) {
    const int brow = w * 64 + mt * 16;
    const short8 a0 = *(const short8*)&mlnL[(brow + c4) * 72 + g * 8];
    const short8 a1 = *(const short8*)&mlnL[(brow + c4) * 72 + 32 + g * 8];
    floatx4 c = {0.f, 0.f, 0.f, 0.f};
    c = __builtin_amdgcn_mfma_f32_16x16x32_bf16(a0, b0, c, 0, 0, 0);
    c = __builtin_amdgcn_mfma_f32_16x16x32_bf16(a1, b1, c, 0, 0, 0);
#pragma unroll
    for (int i = 0; i < 4; ++i)  // C/D: row = g*4+i, col = c4
      kvL[(brow + g * 4 + i) * 16 + c4] = f2bf(c[i]);
  }
  __syncthreads();

  // coalesced kv store: 16 rows x 32 B dense per instruction
#pragma unroll
  for (int jj = 0; jj < 4; ++jj) {
    const int row_local = w * 64 + jj * 16 + (lane >> 2);
    const int s = s_base + row_local;
    const uint2 val = *(const uint2*)&kvL[row_local * 16 + (lane & 3) * 4];
    *(uint2*)(kv + ((size_t)r * S_DIM + s) * 16 + (lane & 3) * 4) = val;
  }
  if (tid < 64)
    qpart[((size_t)r * 8 + blockIdx.x) * 72 + tid] =
        redq[0][tid] + redq[1][tid] + redq[2][tid] + redq[3][tid];
  if (tid == 64)
    qpart[((size_t)r * 8 + blockIdx.x) * 72 + 64] = redc[0] + redc[1] + redc[2] + redc[3];
}

// ---------------- K2: q, logits, softmax, o ----------------
__global__ __launch_bounds__(256) void k2_attn(
    const float* __restrict__ Wq, const float* __restrict__ mask,
    const uint16_t* __restrict__ kv, const float* __restrict__ qpart,
    float* __restrict__ oG)
{
  __shared__ float qavgL[64], qLs[64];
  __shared__ float redmax[4][8], redden[4][8], redo[4][64];
  __shared__ float cntL;
  const int tid = threadIdx.x;
  const int r = blockIdx.x;
  const int lane = tid & 63, wv = tid >> 6;

  float qs = 0.f;
  if (tid < 65) {
#pragma unroll
    for (int c = 0; c < 8; ++c) qs += qpart[((size_t)r * 8 + c) * 72 + tid];
    if (tid == 64) cntL = qs;
  }
  __syncthreads();
  if (tid < 64) qavgL[tid] = qs / (cntL + 1e-10f);
  __syncthreads();
  if (tid < 64) {
    float a = 0.f;
    for (int d = 0; d < 64; ++d) a += qavgL[d] * Wq[d * 64 + tid];
    qLs[tid] = a * 0.35355339059327373f;  // C^-0.5
  }
  __syncthreads();

  float l[64];
  float lm[8];
#pragma unroll
  for (int h = 0; h < 8; ++h) lm[h] = -3.0e38f;
  const uint4* kvp = (const uint4*)kv;
#pragma unroll
  for (int it = 0; it < 8; ++it) {
    const int s = it * 256 + tid;
    uint4 kw = kvp[((size_t)r * S_DIM + s) * 2];
    float k[8]; unpack8(kw, k);
    const float bias = (mask[(size_t)s * R_DIM + r] - 1.f) * 1e9f;
#pragma unroll
    for (int h = 0; h < 8; ++h) {
      float t = bias;
#pragma unroll
      for (int c = 0; c < 8; ++c) t += qLs[h * 8 + c] * k[c];
      l[it * 8 + h] = t;
      lm[h] = fmaxf(lm[h], t);
    }
  }
#pragma unroll
  for (int h = 0; h < 8; ++h)
#pragma unroll
    for (int off = 1; off < 64; off <<= 1) lm[h] = fmaxf(lm[h], __shfl_xor(lm[h], off, 64));
  if (lane == 0) {
#pragma unroll
    for (int h = 0; h < 8; ++h) redmax[wv][h] = lm[h];
  }
  __syncthreads();
  float gm[8];
#pragma unroll
  for (int h = 0; h < 8; ++h)
    gm[h] = fmaxf(fmaxf(redmax[0][h], redmax[1][h]), fmaxf(redmax[2][h], redmax[3][h]));

  float den[8], ao[64];
#pragma unroll
  for (int h = 0; h < 8; ++h) den[h] = 0.f;
#pragma unroll
  for (int i = 0; i < 64; ++i) ao[i] = 0.f;
#pragma unroll
  for (int it = 0; it < 8; ++it) {
    const int s = it * 256 + tid;
    uint4 vw = kvp[((size_t)r * S_DIM + s) * 2 + 1];
    float v[8]; unpack8(vw, v);
#pragma unroll
    for (int h = 0; h < 8; ++h) {
      const float w = __expf(l[it * 8 + h] - gm[h]);
      den[h] += w;
#pragma unroll
      for (int c = 0; c < 8; ++c) ao[h * 8 + c] += w * v[c];
    }
  }
  // fold-exchange ao: lane L ends with the wave sum for hc=L in ao[0]
#pragma unroll
  for (int st = 5; st >= 0; --st) {
    const int dist = 1 << st;
    const bool hi = (lane & dist) != 0;
#pragma unroll
    for (int j = 0; j < (1 << st); ++j) {
      const float send = hi ? ao[j] : ao[j + dist];
      const float recv = __shfl_xor(send, dist, 64);
      ao[j] = (hi ? ao[j + dist] : ao[j]) + recv;
    }
  }
#pragma unroll
  for (int h = 0; h < 8; ++h)
#pragma unroll
    for (int off = 1; off < 64; off <<= 1) den[h] += __shfl_xor(den[h], off, 64);

  redo[wv][lane] = ao[0];
  if (lane == 0) {
#pragma unroll
    for (int h = 0; h < 8; ++h) redden[wv][h] = den[h];
  }
  __syncthreads();
  if (tid < 64) {
    const float o = redo[0][tid] + redo[1][tid] + redo[2][tid] + redo[3][tid];
    const int h = tid >> 3;
    const float dd = redden[0][h] + redden[1][h] + redden[2][h] + redden[3][h];
    oG[(size_t)r * 64 + tid] = o / dd;
  }
}

// ---------------- K3: LN -> MFMA gate -> MFMA out -> residual ----------------
__global__ __launch_bounds__(256, 2) void k3_out(
    const float* __restrict__ M, const float* __restrict__ stats,
    const float* __restrict__ oG,
    const float* __restrict__ Wg, const float* __restrict__ bg,
    const float* __restrict__ Wo, const float* __restrict__ bo,
    const float* __restrict__ lng, const float* __restrict__ lnb,
    float* __restrict__ out)
{
  __shared__ uint16_t mlnL[256 * 72];  // mln -> gate-T -> OUT (wave-local rows)
  __shared__ uint16_t WgT[64 * 72];    // WgT[hc][d] = Wg[d][hc]
  __shared__ uint16_t WoT[64 * 72];    // WoT[d][hc] = Wo[hc][d]
  __shared__ float oLs[64];
  const int tid = threadIdx.x;
  const int r = blockIdx.y;
  const int s_base = blockIdx.x * 256;
  const int w = tid >> 6, lane = tid & 63;
  const int g = lane >> 4, c4 = lane & 15;

#pragma unroll
  for (int i = 0; i < 16; ++i) {
    const int idx = i * 256 + tid;           // 4096 weight elems
    const int a = idx >> 6, b = idx & 63;
    WgT[b * 72 + a] = f2bf(Wg[idx]);         // a=d, b=hc
    WoT[b * 72 + a] = f2bf(Wo[idx]);         // a=hc, b=d
  }
  if (tid < 64) oLs[tid] = oG[(size_t)r * 64 + tid];
  const float4 lngv = ((const float4*)lng)[c4];
  const float4 lnbv = ((const float4*)lnb)[c4];

  // phase 1: coalesced load + LN -> mlnL
#pragma unroll
  for (int j = 0; j < 16; ++j) {
    const int row_local = w * 64 + j * 4 + g;
    const int s = s_base + row_local;
    const size_t grow = (size_t)s * R_DIM + r;
    const float2 st = ((const float2*)stats)[(size_t)r * S_DIM + s];
    const float4 x = ((const float4*)(M + grow * 64))[c4];
    float y[4];
    y[0] = (x.x - st.x) * st.y * lngv.x + lnbv.x;
    y[1] = (x.y - st.x) * st.y * lngv.y + lnbv.y;
    y[2] = (x.z - st.x) * st.y * lngv.z + lnbv.z;
    y[3] = (x.w - st.x) * st.y * lngv.w + lnbv.w;
    uint2 p;
    p.x = (uint32_t)f2bf(y[0]) | ((uint32_t)f2bf(y[1]) << 16);
    p.y = (uint32_t)f2bf(y[2]) | ((uint32_t)f2bf(y[3]) << 16);
    *(uint2*)&mlnL[row_local * 72 + c4 * 4] = p;
  }
  __syncthreads();

  const int wrow0 = w * 64;
  const int mrow = c4;   // n / col index
  const int quad = g;

  // B fragments: B[k = quad*8+j (+32*kk)][n = mrow]
  short8 wgB[4][2], woB[4][2];
#pragma unroll
  for (int nt = 0; nt < 4; ++nt)
#pragma unroll
    for (int kk = 0; kk < 2; ++kk) {
      wgB[nt][kk] = *(const short8*)(&WgT[(nt * 16 + mrow) * 72 + kk * 32 + quad * 8]);
      woB[nt][kk] = *(const short8*)(&WoT[(nt * 16 + mrow) * 72 + kk * 32 + quad * 8]);
    }
  float og[4], bgr[4], bor[4];
#pragma unroll
  for (int nt = 0; nt < 4; ++nt) {
    og[nt] = oLs[nt * 16 + mrow];
    bgr[nt] = bg[nt * 16 + mrow];
    bor[nt] = bo[nt * 16 + mrow];
  }

  // GEMM1: G = mln @ Wg ; T = sigmoid(G+bg)*o -> mlnL (C/D scatter)
#pragma unroll
  for (int mt = 0; mt < 4; ++mt) {
    const int arow = (wrow0 + mt * 16 + mrow) * 72 + quad * 8;
    const short8 a0 = *(const short8*)(&mlnL[arow]);
    const short8 a1 = *(const short8*)(&mlnL[arow + 32]);
#pragma unroll
    for (int nt = 0; nt < 4; ++nt) {
      floatx4 c = {0.f, 0.f, 0.f, 0.f};
      c = __builtin_amdgcn_mfma_f32_16x16x32_bf16(a0, wgB[nt][0], c, 0, 0, 0);
      c = __builtin_amdgcn_mfma_f32_16x16x32_bf16(a1, wgB[nt][1], c, 0, 0, 0);
#pragma unroll
      for (int i = 0; i < 4; ++i) {  // C/D: row = quad*4+i, col = mrow
        const float z = c[i] + bgr[nt];
        const float gt = 1.0f / (1.0f + __expf(-z));
        mlnL[(wrow0 + mt * 16 + quad * 4 + i) * 72 + nt * 16 + mrow] = f2bf(gt * og[nt]);
      }
    }
  }
  __syncthreads();

  // GEMM2: OUT = T @ Wo + bo -> mlnL
#pragma unroll
  for (int mt = 0; mt < 4; ++mt) {
    const int arow = (wrow0 + mt * 16 + mrow) * 72 + quad * 8;
    const short8 a0 = *(const short8*)(&mlnL[arow]);
    const short8 a1 = *(const short8*)(&mlnL[arow + 32]);
#pragma unroll
    for (int nt = 0; nt < 4; ++nt) {
      floatx4 c = {0.f, 0.f, 0.f, 0.f};
      c = __builtin_amdgcn_mfma_f32_16x16x32_bf16(a0, woB[nt][0], c, 0, 0, 0);
      c = __builtin_amdgcn_mfma_f32_16x16x32_bf16(a1, woB[nt][1], c, 0, 0, 0);
#pragma unroll
      for (int i = 0; i < 4; ++i)
        mlnL[(wrow0 + mt * 16 + quad * 4 + i) * 72 + nt * 16 + mrow] = f2bf(c[i] + bor[nt]);
    }
  }
  __syncthreads();

  // epilogue: residual + coalesced store (same 4-row-dense mapping as phase 1)
#pragma unroll
  for (int j = 0; j < 16; ++j) {
    const int row_local = w * 64 + j * 4 + g;
    const int s = s_base + row_local;
    const size_t grow = (size_t)s * R_DIM + r;
    const float4 x = ((const float4*)(M + grow * 64))[c4];
    const uint2 tv = *(const uint2*)&mlnL[row_local * 72 + c4 * 4];
    float4 o;
    o.x = x.x + bf2f(tv.x & 0xffff);
    o.y = x.y + bf2f(tv.x >> 16);
    o.z = x.z + bf2f(tv.y & 0xffff);
    o.w = x.w + bf2f(tv.y >> 16);
    ((float4*)(out + grow * 64))[c4] = o;
  }
}

extern "C" void kernel_launch(void* const* d_in, const int* in_sizes, int n_in,
                              void* d_out, int out_size, void* d_ws, size_t ws_size,
                              hipStream_t stream)
{
  const float* M    = (const float*)d_in[0];
  const float* mask = (const float*)d_in[1];
  const float* lng  = (const float*)d_in[2];
  const float* lnb  = (const float*)d_in[3];
  const float* Wq   = (const float*)d_in[4];
  const float* Wk   = (const float*)d_in[5];
  const float* Wv   = (const float*)d_in[6];
  const float* Wg   = (const float*)d_in[7];
  const float* bg   = (const float*)d_in[8];
  const float* Wo   = (const float*)d_in[9];
  const float* bo   = (const float*)d_in[10];
  float* out = (float*)d_out;

  char* ws = (char*)d_ws;
  uint16_t* kvB  = (uint16_t*)(ws + KV_OFF);
  float* statsB  = (float*)(ws + STATS_OFF);
  float* qpartB  = (float*)(ws + QPART_OFF);
  float* oB      = (float*)(ws + O_OFF);

  k1_ln_kv<<<dim3(8, 384), 256, 0, stream>>>(M, mask, lng, lnb, Wk, Wv, kvB, statsB, qpartB);
  k2_attn<<<dim3(384), 256, 0, stream>>>(Wq, mask, kvB, qpartB, oB);
  k3_out<<<dim3(8, 384), 256, 0, stream>>>(M, statsB, oB, Wg, bg, Wo, bo, lng, lnb, out);
}